// Round 1
// baseline (419.843 us; speedup 1.0000x reference)
//
#include <hip/hip_runtime.h>
#include <math.h>

#define BATCH 4
#define NPTS 8192
#define SEG 2
#define SEGLEN (NPTS / SEG)

// ---------------------------------------------------------------------------
// Kernel 1: warp xyz1 by flow1, pack as float4 (x,y,z,pad) for 16B loads.
// ---------------------------------------------------------------------------
__global__ __launch_bounds__(256) void prep_kernel(
    const float* __restrict__ xyz1, const float* __restrict__ flow1,
    float4* __restrict__ cand)
{
    int t = blockIdx.x * 256 + threadIdx.x;        // BATCH*NPTS threads exactly
    int b = t >> 13;
    int n = t & (NPTS - 1);
    const float* x = xyz1 + b * 3 * NPTS + n;
    const float* f = flow1 + b * 3 * NPTS + n;
    float wx = x[0]        + f[0];
    float wy = x[NPTS]     + f[NPTS];
    float wz = x[2 * NPTS] + f[2 * NPTS];
    cand[t] = make_float4(wx, wy, wz, 0.0f);
}

// ---------------------------------------------------------------------------
// Kernel 2: brute-force partial 3-NN scan. One thread per query; candidate
// axis split SEG ways across blocks (1024 waves total = 1 wave/SIMD).
// Candidate index k is wave-uniform -> compiler scalarizes loads (s_load).
// Strict '<' keeps lowest index on distance ties (matches top_k tie-break).
// ---------------------------------------------------------------------------
__global__ __launch_bounds__(256) void scan_kernel(
    const float* __restrict__ xyz2, const float4* __restrict__ cand,
    float* __restrict__ pd, int* __restrict__ pi)
{
    int blk = blockIdx.x;              // = b*64 + qt*2 + seg
    int seg = blk & (SEG - 1);
    int qt  = (blk >> 1) & 31;         // NPTS/256 = 32 query tiles
    int b   = blk >> 6;
    int j   = qt * 256 + (int)threadIdx.x;

    const float* q = xyz2 + b * 3 * NPTS + j;
    float qx = q[0], qy = q[NPTS], qz = q[2 * NPTS];

    const float4* cb = cand + b * NPTS + seg * SEGLEN;

    float e0 = 3.4e38f, e1 = 3.4e38f, e2 = 3.4e38f;
    int   i0 = 0, i1 = 0, i2 = 0;

    #pragma unroll 4
    for (int k = 0; k < SEGLEN; ++k) {
        float4 c = cb[k];
        float dx = c.x - qx;
        float dy = c.y - qy;
        float dz = c.z - qz;
        float d  = fmaf(dx, dx, fmaf(dy, dy, dz * dz));
        if (d < e2) {                          // rarely taken after warm-up
            if (d < e1) {
                e2 = e1; i2 = i1;
                if (d < e0) { e1 = e0; i1 = i0; e0 = d; i0 = k; }
                else        { e1 = d;  i1 = k; }
            } else {
                e2 = d; i2 = k;
            }
        }
    }

    int off = seg * SEGLEN;
    size_t base = ((size_t)(b * SEG + seg) * NPTS + j) * 3;
    pd[base] = e0;       pd[base + 1] = e1;       pd[base + 2] = e2;
    pi[base] = i0 + off; pi[base + 1] = i1 + off; pi[base + 2] = i2 + off;
}

// ---------------------------------------------------------------------------
// Kernel 3: merge SEG partial top-3s, compute inverse-distance weights,
// gather flows, write warped output [B,3,N2].
// ---------------------------------------------------------------------------
__device__ __forceinline__ void insert3(float d, int idx,
    float& e0, float& e1, float& e2, int& i0, int& i1, int& i2)
{
    if (d < e2) {
        if (d < e1) {
            e2 = e1; i2 = i1;
            if (d < e0) { e1 = e0; i1 = i0; e0 = d; i0 = idx; }
            else        { e1 = d;  i1 = idx; }
        } else {
            e2 = d; i2 = idx;
        }
    }
}

__global__ __launch_bounds__(256) void finalize_kernel(
    const float* __restrict__ xyz2, const float* __restrict__ flow1,
    const float4* __restrict__ cand,
    const float* __restrict__ pd, const int* __restrict__ pi,
    float* __restrict__ out)
{
    int t = blockIdx.x * 256 + threadIdx.x;    // BATCH*NPTS threads
    int b = t >> 13;
    int j = t & (NPTS - 1);

    size_t base0 = ((size_t)(b * SEG + 0) * NPTS + j) * 3;
    size_t base1 = ((size_t)(b * SEG + 1) * NPTS + j) * 3;

    float e0 = pd[base0], e1 = pd[base0 + 1], e2 = pd[base0 + 2];
    int   i0 = pi[base0], i1 = pi[base0 + 1], i2 = pi[base0 + 2];

    // seg-0 entries have lower global indices; strict '<' gives them tie priority
    insert3(pd[base1],     pi[base1],     e0, e1, e2, i0, i1, i2);
    insert3(pd[base1 + 1], pi[base1 + 1], e0, e1, e2, i0, i1, i2);
    insert3(pd[base1 + 2], pi[base1 + 2], e0, e1, e2, i0, i1, i2);

    const float* q = xyz2 + b * 3 * NPTS + j;
    float qx = q[0], qy = q[NPTS], qz = q[2 * NPTS];

    const float4* cb = cand + b * NPTS;
    const float*  fb = flow1 + b * 3 * NPTS;

    float wsum = 0.f, f2x = 0.f, f2y = 0.f, f2z = 0.f;
    int idxs[3] = { i0, i1, i2 };
    #pragma unroll
    for (int k = 0; k < 3; ++k) {
        int id = idxs[k];
        float4 c = cb[id];
        float dx = c.x - qx, dy = c.y - qy, dz = c.z - qz;
        float dist = sqrtf(fmaf(dx, dx, fmaf(dy, dy, dz * dz)));
        dist = fmaxf(dist, 1e-10f);
        float w = 1.0f / dist;
        wsum += w;
        f2x = fmaf(w, fb[id],            f2x);
        f2y = fmaf(w, fb[NPTS + id],     f2y);
        f2z = fmaf(w, fb[2 * NPTS + id], f2z);
    }
    float r = 1.0f / wsum;
    float* ob = out + b * 3 * NPTS;
    ob[j]            = qx - f2x * r;
    ob[NPTS + j]     = qy - f2y * r;
    ob[2 * NPTS + j] = qz - f2z * r;
}

// ---------------------------------------------------------------------------
// Launcher. Workspace layout:
//   [0, 512KB)            float4 cand[BATCH*NPTS]   (warped points)
//   [512KB, 512KB+768KB)  float  pd[BATCH*SEG*NPTS*3]
//   [+768KB, +768KB)      int    pi[BATCH*SEG*NPTS*3]
// Total 2 MB.
// ---------------------------------------------------------------------------
extern "C" void kernel_launch(void* const* d_in, const int* in_sizes, int n_in,
                              void* d_out, int out_size, void* d_ws, size_t ws_size,
                              hipStream_t stream)
{
    const float* xyz1  = (const float*)d_in[0];
    const float* xyz2  = (const float*)d_in[1];
    const float* flow1 = (const float*)d_in[2];
    float* out = (float*)d_out;

    const size_t CAND_BYTES = (size_t)BATCH * NPTS * sizeof(float4);
    const size_t PD_BYTES   = (size_t)BATCH * SEG * NPTS * 3 * sizeof(float);

    float4* cand = (float4*)d_ws;
    float*  pd   = (float*)((char*)d_ws + CAND_BYTES);
    int*    pi   = (int*)((char*)d_ws + CAND_BYTES + PD_BYTES);

    prep_kernel<<<BATCH * NPTS / 256, 256, 0, stream>>>(xyz1, flow1, cand);
    scan_kernel<<<BATCH * (NPTS / 256) * SEG, 256, 0, stream>>>(xyz2, cand, pd, pi);
    finalize_kernel<<<BATCH * NPTS / 256, 256, 0, stream>>>(xyz2, flow1, cand, pd, pi, out);
}

// Round 2
// 147.876 us; speedup vs baseline: 2.8392x; 2.8392x over previous
//
#include <hip/hip_runtime.h>
#include <math.h>

#define BATCH 4
#define NPTS 8192
#define QPB 16                 // queries per block
#define SEGB 16                // candidate segments per block
#define SEGLEN (NPTS / SEGB)   // 512 candidates per segment

// ---------------------------------------------------------------------------
// Kernel 1: warp xyz1 by flow1, pack as float4 (x,y,z,pad) for 16B loads.
// ---------------------------------------------------------------------------
__global__ __launch_bounds__(256) void prep_kernel(
    const float* __restrict__ xyz1, const float* __restrict__ flow1,
    float4* __restrict__ cand)
{
    int t = blockIdx.x * 256 + threadIdx.x;        // BATCH*NPTS threads exactly
    int b = t >> 13;
    int n = t & (NPTS - 1);
    const float* x = xyz1 + b * 3 * NPTS + n;
    const float* f = flow1 + b * 3 * NPTS + n;
    float wx = x[0]        + f[0];
    float wy = x[NPTS]     + f[NPTS];
    float wz = x[2 * NPTS] + f[2 * NPTS];
    cand[t] = make_float4(wx, wy, wz, 0.0f);
}

// ---------------------------------------------------------------------------
// Kernel 2: fused scan + merge + finalize.
// Block = 256 threads = QPB(16) queries x SEGB(16) segments.
//   thread t: query q = t & 15 (lane-varying), segment seg = t >> 4
//   -> within a wave, 4 distinct candidate addresses (16-lane broadcast each)
// Each thread keeps a top-3 over its 512-candidate segment; partials merged
// via LDS in ascending-segment order (strict '<' => lowest index wins ties),
// then 16 threads do the inverse-distance-weight epilogue.
// Grid: BATCH * NPTS/QPB = 2048 blocks -> 8192 waves = 8/SIMD (full occupancy).
// ---------------------------------------------------------------------------
__device__ __forceinline__ void insert3(float d, int idx,
    float& e0, float& e1, float& e2, int& i0, int& i1, int& i2)
{
    if (d < e2) {
        if (d < e1) {
            e2 = e1; i2 = i1;
            if (d < e0) { e1 = e0; i1 = i0; e0 = d; i0 = idx; }
            else        { e1 = d;  i1 = idx; }
        } else {
            e2 = d; i2 = idx;
        }
    }
}

__global__ __launch_bounds__(256) void scan_merge_kernel(
    const float* __restrict__ xyz2, const float* __restrict__ flow1,
    const float4* __restrict__ cand, float* __restrict__ out)
{
    __shared__ float ldsd[QPB][SEGB * 3];
    __shared__ int   ldsi[QPB][SEGB * 3];

    int t     = (int)threadIdx.x;
    int q     = t & (QPB - 1);
    int seg   = t >> 4;
    int b     = blockIdx.x >> 9;           // NPTS/QPB = 512 blocks per batch
    int qtile = blockIdx.x & 511;
    int j     = qtile * QPB + q;

    const float* qp = xyz2 + b * 3 * NPTS + j;
    float qx = qp[0], qy = qp[NPTS], qz = qp[2 * NPTS];

    const float4* cb = cand + b * NPTS + seg * SEGLEN;

    float e0 = 3.4e38f, e1 = 3.4e38f, e2 = 3.4e38f;
    int   i0 = 0, i1 = 0, i2 = 0;

    #pragma unroll 8
    for (int k = 0; k < SEGLEN; ++k) {
        float4 c = cb[k];
        float dx = c.x - qx;
        float dy = c.y - qy;
        float dz = c.z - qz;
        float d  = fmaf(dx, dx, fmaf(dy, dy, dz * dz));
        if (d < e2) {                      // rarely taken after warm-up
            if (d < e1) {
                e2 = e1; i2 = i1;
                if (d < e0) { e1 = e0; i1 = i0; e0 = d; i0 = k; }
                else        { e1 = d;  i1 = k; }
            } else {
                e2 = d; i2 = k;
            }
        }
    }

    int off = seg * SEGLEN;
    ldsd[q][seg * 3 + 0] = e0;  ldsi[q][seg * 3 + 0] = i0 + off;
    ldsd[q][seg * 3 + 1] = e1;  ldsi[q][seg * 3 + 1] = i1 + off;
    ldsd[q][seg * 3 + 2] = e2;  ldsi[q][seg * 3 + 2] = i2 + off;
    __syncthreads();

    if (t < QPB) {
        // merge 16 partial top-3s in ascending segment order
        float m0 = 3.4e38f, m1 = 3.4e38f, m2 = 3.4e38f;
        int   n0 = 0, n1 = 0, n2 = 0;
        #pragma unroll
        for (int e = 0; e < SEGB * 3; ++e)
            insert3(ldsd[t][e], ldsi[t][e], m0, m1, m2, n0, n1, n2);

        int jj = qtile * QPB + t;
        const float* qp2 = xyz2 + b * 3 * NPTS + jj;
        float px = qp2[0], py = qp2[NPTS], pz = qp2[2 * NPTS];

        const float4* cbb = cand + b * NPTS;
        const float*  fb  = flow1 + b * 3 * NPTS;

        float wsum = 0.f, f2x = 0.f, f2y = 0.f, f2z = 0.f;
        int idxs[3] = { n0, n1, n2 };
        #pragma unroll
        for (int k = 0; k < 3; ++k) {
            int id = idxs[k];
            float4 c = cbb[id];
            float dx = c.x - px, dy = c.y - py, dz = c.z - pz;
            float dist = sqrtf(fmaf(dx, dx, fmaf(dy, dy, dz * dz)));
            dist = fmaxf(dist, 1e-10f);
            float w = 1.0f / dist;
            wsum += w;
            f2x = fmaf(w, fb[id],            f2x);
            f2y = fmaf(w, fb[NPTS + id],     f2y);
            f2z = fmaf(w, fb[2 * NPTS + id], f2z);
        }
        float r = 1.0f / wsum;
        float* ob = out + b * 3 * NPTS;
        ob[jj]            = px - f2x * r;
        ob[NPTS + jj]     = py - f2y * r;
        ob[2 * NPTS + jj] = pz - f2z * r;
    }
}

// ---------------------------------------------------------------------------
// Launcher. Workspace: float4 cand[BATCH*NPTS] = 512 KB.
// ---------------------------------------------------------------------------
extern "C" void kernel_launch(void* const* d_in, const int* in_sizes, int n_in,
                              void* d_out, int out_size, void* d_ws, size_t ws_size,
                              hipStream_t stream)
{
    const float* xyz1  = (const float*)d_in[0];
    const float* xyz2  = (const float*)d_in[1];
    const float* flow1 = (const float*)d_in[2];
    float* out = (float*)d_out;

    float4* cand = (float4*)d_ws;

    prep_kernel<<<BATCH * NPTS / 256, 256, 0, stream>>>(xyz1, flow1, cand);
    scan_merge_kernel<<<BATCH * (NPTS / QPB), 256, 0, stream>>>(xyz2, flow1, cand, out);
}

// Round 3
// 141.559 us; speedup vs baseline: 2.9659x; 1.0446x over previous
//
#include <hip/hip_runtime.h>
#include <math.h>

#define BATCH 4
#define NPTS 8192
#define QPB 32                 // queries per block
#define SEGB 8                 // candidate segments per block
#define SEGLEN (NPTS / SEGB)   // 1024 candidates per thread

// ---------------------------------------------------------------------------
// Kernel 1: warp xyz1 by flow1, pack as float4 (x,y,z,pad) for 16B loads.
// ---------------------------------------------------------------------------
__global__ __launch_bounds__(256) void prep_kernel(
    const float* __restrict__ xyz1, const float* __restrict__ flow1,
    float4* __restrict__ cand)
{
    int t = blockIdx.x * 256 + threadIdx.x;        // BATCH*NPTS threads exactly
    int b = t >> 13;
    int n = t & (NPTS - 1);
    const float* x = xyz1 + b * 3 * NPTS + n;
    const float* f = flow1 + b * 3 * NPTS + n;
    float wx = x[0]        + f[0];
    float wy = x[NPTS]     + f[NPTS];
    float wz = x[2 * NPTS] + f[2 * NPTS];
    cand[t] = make_float4(wx, wy, wz, 0.0f);
}

// ---------------------------------------------------------------------------
// Kernel 2: fused scan + merge + finalize.
// Block = 256 threads = QPB(32) queries x SEGB(8) segments; thread t handles
// query (t&31) against segment (t>>5) of 1024 candidates.
//   - single-guard branchless insert: one saveexec level, 12 VALU when taken;
//     wave-level taken fraction ~50% at lambda=1024 (~74% at 512).
//   - explicit 4-deep prefetch (static reg indexing) to hide L2 latency at
//     4 waves/SIMD (grid = 1024 blocks = 4096 waves).
//   - LDS merge arrays padded to stride 25 floats -> conflict-free.
// Tie-break: segments merged in ascending index order with strict '<', so the
// lowest global index wins ties, matching top_k.
// ---------------------------------------------------------------------------
#define PROC(c, kk) do {                                              \
    float dx = (c).x - qx, dy = (c).y - qy, dz = (c).z - qz;          \
    float d  = fmaf(dx, dx, fmaf(dy, dy, dz * dz));                   \
    if (d < e2) {                                                     \
        bool c1 = d < e1, c0 = d < e0;                                \
        e2 = c1 ? e1 : d;   i2 = c1 ? i1 : (kk);                      \
        e1 = c0 ? e0 : (c1 ? d : e1);                                 \
        i1 = c0 ? i0 : (c1 ? (kk) : i1);                              \
        e0 = c0 ? d : e0;   i0 = c0 ? (kk) : i0;                      \
    }                                                                 \
} while (0)

__device__ __forceinline__ void insert3(float d, int idx,
    float& e0, float& e1, float& e2, int& i0, int& i1, int& i2)
{
    if (d < e2) {
        bool c1 = d < e1, c0 = d < e0;
        e2 = c1 ? e1 : d;   i2 = c1 ? i1 : idx;
        e1 = c0 ? e0 : (c1 ? d : e1);
        i1 = c0 ? i0 : (c1 ? idx : i1);
        e0 = c0 ? d : e0;   i0 = c0 ? idx : i0;
    }
}

__global__ __launch_bounds__(256) void scan_merge_kernel(
    const float* __restrict__ xyz2, const float* __restrict__ flow1,
    const float4* __restrict__ cand, float* __restrict__ out)
{
    __shared__ float ldsd[QPB][SEGB * 3 + 1];   // stride 25 -> no bank conflict
    __shared__ int   ldsi[QPB][SEGB * 3 + 1];

    int t     = (int)threadIdx.x;
    int q     = t & (QPB - 1);
    int seg   = t >> 5;
    int b     = blockIdx.x >> 8;           // NPTS/QPB = 256 blocks per batch
    int qtile = blockIdx.x & 255;
    int j     = qtile * QPB + q;

    const float* qp = xyz2 + b * 3 * NPTS + j;
    float qx = qp[0], qy = qp[NPTS], qz = qp[2 * NPTS];

    const float4* cb = cand + b * NPTS + seg * SEGLEN;

    float e0 = 3.4e38f, e1 = 3.4e38f, e2 = 3.4e38f;
    int   i0 = 0, i1 = 0, i2 = 0;

    // 4-deep software prefetch, static register indexing only
    float4 p0 = cb[0], p1 = cb[1], p2 = cb[2], p3 = cb[3];
    for (int k = 0; k < SEGLEN - 4; k += 4) {
        float4 n0 = cb[k + 4], n1 = cb[k + 5], n2 = cb[k + 6], n3 = cb[k + 7];
        PROC(p0, k + 0);
        PROC(p1, k + 1);
        PROC(p2, k + 2);
        PROC(p3, k + 3);
        p0 = n0; p1 = n1; p2 = n2; p3 = n3;
    }
    PROC(p0, SEGLEN - 4);
    PROC(p1, SEGLEN - 3);
    PROC(p2, SEGLEN - 2);
    PROC(p3, SEGLEN - 1);

    int off = seg * SEGLEN;
    ldsd[q][seg * 3 + 0] = e0;  ldsi[q][seg * 3 + 0] = i0 + off;
    ldsd[q][seg * 3 + 1] = e1;  ldsi[q][seg * 3 + 1] = i1 + off;
    ldsd[q][seg * 3 + 2] = e2;  ldsi[q][seg * 3 + 2] = i2 + off;
    __syncthreads();

    if (t < QPB) {
        // merge 8 partial top-3s in ascending segment order (tie -> low index)
        float m0 = 3.4e38f, m1 = 3.4e38f, m2 = 3.4e38f;
        int   n0 = 0, n1 = 0, n2 = 0;
        #pragma unroll
        for (int e = 0; e < SEGB * 3; ++e)
            insert3(ldsd[t][e], ldsi[t][e], m0, m1, m2, n0, n1, n2);

        int jj = qtile * QPB + t;
        const float* qp2 = xyz2 + b * 3 * NPTS + jj;
        float px = qp2[0], py = qp2[NPTS], pz = qp2[2 * NPTS];

        const float4* cbb = cand + b * NPTS;
        const float*  fb  = flow1 + b * 3 * NPTS;

        float wsum = 0.f, f2x = 0.f, f2y = 0.f, f2z = 0.f;
        int idxs[3] = { n0, n1, n2 };
        #pragma unroll
        for (int k = 0; k < 3; ++k) {
            int id = idxs[k];
            float4 c = cbb[id];
            float dx = c.x - px, dy = c.y - py, dz = c.z - pz;
            float dist = sqrtf(fmaf(dx, dx, fmaf(dy, dy, dz * dz)));
            dist = fmaxf(dist, 1e-10f);
            float w = 1.0f / dist;
            wsum += w;
            f2x = fmaf(w, fb[id],            f2x);
            f2y = fmaf(w, fb[NPTS + id],     f2y);
            f2z = fmaf(w, fb[2 * NPTS + id], f2z);
        }
        float r = 1.0f / wsum;
        float* ob = out + b * 3 * NPTS;
        ob[jj]            = px - f2x * r;
        ob[NPTS + jj]     = py - f2y * r;
        ob[2 * NPTS + jj] = pz - f2z * r;
    }
}

// ---------------------------------------------------------------------------
// Launcher. Workspace: float4 cand[BATCH*NPTS] = 512 KB.
// ---------------------------------------------------------------------------
extern "C" void kernel_launch(void* const* d_in, const int* in_sizes, int n_in,
                              void* d_out, int out_size, void* d_ws, size_t ws_size,
                              hipStream_t stream)
{
    const float* xyz1  = (const float*)d_in[0];
    const float* xyz2  = (const float*)d_in[1];
    const float* flow1 = (const float*)d_in[2];
    float* out = (float*)d_out;

    float4* cand = (float4*)d_ws;

    prep_kernel<<<BATCH * NPTS / 256, 256, 0, stream>>>(xyz1, flow1, cand);
    scan_merge_kernel<<<BATCH * (NPTS / QPB), 256, 0, stream>>>(xyz2, flow1, cand, out);
}

// Round 4
// 135.987 us; speedup vs baseline: 3.0874x; 1.0410x over previous
//
#include <hip/hip_runtime.h>
#include <math.h>

#define BATCH 4
#define NPTS 8192
#define QPB 16                 // queries per block
#define SEGB 16                // candidate segments per block
#define SEGLEN (NPTS / SEGB)   // 512 candidates per thread

// ---------------------------------------------------------------------------
// Kernel 1: warp xyz1 by flow1, pack as (-2x, -2y, -2z, |c|^2) so the scan's
// comparison key is 3 FMAs: d' = |c|^2 - 2<c,q>  (= |c-q|^2 - |q|^2, same
// ordering per query; identical expansion form to the reference's selection).
// Positions are recovered in the epilogue as x = -0.5 * key.x (exact).
// ---------------------------------------------------------------------------
__global__ __launch_bounds__(256) void prep_kernel(
    const float* __restrict__ xyz1, const float* __restrict__ flow1,
    float4* __restrict__ cand)
{
    int t = blockIdx.x * 256 + threadIdx.x;        // BATCH*NPTS threads exactly
    int b = t >> 13;
    int n = t & (NPTS - 1);
    const float* x = xyz1 + b * 3 * NPTS + n;
    const float* f = flow1 + b * 3 * NPTS + n;
    float wx = x[0]        + f[0];
    float wy = x[NPTS]     + f[NPTS];
    float wz = x[2 * NPTS] + f[2 * NPTS];
    float nrm = fmaf(wx, wx, fmaf(wy, wy, wz * wz));
    cand[t] = make_float4(-2.0f * wx, -2.0f * wy, -2.0f * wz, nrm);
}

// ---------------------------------------------------------------------------
// Kernel 2: fused scan + merge + finalize.
// Block = 256 threads = QPB(16) queries x SEGB(16) segments; thread t scans
// segment (t>>4) of 512 candidates for query (t&15).
// Grid = 2048 blocks = 8192 waves = 8 waves/SIMD (full occupancy for TLP).
// Inner loop is fully branchless (we accept if-conversion and minimize it):
//   3 FMA key + {min, med3, med3} sorted-value update + 3 cmp + 5 cndmask
//   index update ~= 15-16 VALU per candidate.
// Strict '<' keeps the incumbent (lower index) on ties, matching top_k.
// ---------------------------------------------------------------------------
__device__ __forceinline__ void insert3(float d, int idx,
    float& e0, float& e1, float& e2, int& i0, int& i1, int& i2)
{
    if (d < e2) {
        bool c1 = d < e1, c0 = d < e0;
        e2 = c1 ? e1 : d;   i2 = c1 ? i1 : idx;
        e1 = c0 ? e0 : (c1 ? d : e1);
        i1 = c0 ? i0 : (c1 ? idx : i1);
        e0 = c0 ? d : e0;   i0 = c0 ? idx : i0;
    }
}

__global__ __launch_bounds__(256) void scan_merge_kernel(
    const float* __restrict__ xyz2, const float* __restrict__ flow1,
    const float4* __restrict__ cand, float* __restrict__ out)
{
    __shared__ float ldsd[QPB][SEGB * 3 + 1];   // stride 49 -> no bank conflicts
    __shared__ int   ldsi[QPB][SEGB * 3 + 1];

    int t     = (int)threadIdx.x;
    int q     = t & (QPB - 1);
    int seg   = t >> 4;
    int b     = blockIdx.x >> 9;           // NPTS/QPB = 512 blocks per batch
    int qtile = blockIdx.x & 511;
    int j     = qtile * QPB + q;

    const float* qp = xyz2 + b * 3 * NPTS + j;
    float qx = qp[0], qy = qp[NPTS], qz = qp[2 * NPTS];

    const float4* cb = cand + b * NPTS + seg * SEGLEN;

    float e0 = 3.4e38f, e1 = 3.4e38f, e2 = 3.4e38f;
    int   i0 = 0, i1 = 0, i2 = 0;

    #pragma unroll 8
    for (int k = 0; k < SEGLEN; ++k) {
        float4 c = cb[k];
        float d = fmaf(c.x, qx, fmaf(c.y, qy, fmaf(c.z, qz, c.w)));
        bool c0 = d < e0, c1 = d < e1, c2 = d < e2;
        float ne0 = fminf(e0, d);
        float ne1 = __builtin_amdgcn_fmed3f(e0, e1, d);  // 2nd smallest of {e0,e1,e2,d}
        float ne2 = __builtin_amdgcn_fmed3f(e1, e2, d);  // 3rd smallest
        i2 = c1 ? i1 : (c2 ? k : i2);
        i1 = c0 ? i0 : (c1 ? k : i1);
        i0 = c0 ? k : i0;
        e0 = ne0; e1 = ne1; e2 = ne2;
    }

    int off = seg * SEGLEN;
    ldsd[q][seg * 3 + 0] = e0;  ldsi[q][seg * 3 + 0] = i0 + off;
    ldsd[q][seg * 3 + 1] = e1;  ldsi[q][seg * 3 + 1] = i1 + off;
    ldsd[q][seg * 3 + 2] = e2;  ldsi[q][seg * 3 + 2] = i2 + off;
    __syncthreads();

    if (t < QPB) {
        // merge 16 partial top-3s in ascending segment order (tie -> low index)
        float m0 = 3.4e38f, m1 = 3.4e38f, m2 = 3.4e38f;
        int   n0 = 0, n1 = 0, n2 = 0;
        #pragma unroll
        for (int e = 0; e < SEGB * 3; ++e)
            insert3(ldsd[t][e], ldsi[t][e], m0, m1, m2, n0, n1, n2);

        int jj = qtile * QPB + t;
        const float* qp2 = xyz2 + b * 3 * NPTS + jj;
        float px = qp2[0], py = qp2[NPTS], pz = qp2[2 * NPTS];

        const float4* cbb = cand + b * NPTS;
        const float*  fb  = flow1 + b * 3 * NPTS;

        float wsum = 0.f, f2x = 0.f, f2y = 0.f, f2z = 0.f;
        int idxs[3] = { n0, n1, n2 };
        #pragma unroll
        for (int k = 0; k < 3; ++k) {
            int id = idxs[k];
            float4 c = cbb[id];
            float cx = -0.5f * c.x, cy = -0.5f * c.y, cz = -0.5f * c.z;
            float dx = cx - px, dy = cy - py, dz = cz - pz;
            float dist = sqrtf(fmaf(dx, dx, fmaf(dy, dy, dz * dz)));
            dist = fmaxf(dist, 1e-10f);
            float w = 1.0f / dist;
            wsum += w;
            f2x = fmaf(w, fb[id],            f2x);
            f2y = fmaf(w, fb[NPTS + id],     f2y);
            f2z = fmaf(w, fb[2 * NPTS + id], f2z);
        }
        float r = 1.0f / wsum;
        float* ob = out + b * 3 * NPTS;
        ob[jj]            = px - f2x * r;
        ob[NPTS + jj]     = py - f2y * r;
        ob[2 * NPTS + jj] = pz - f2z * r;
    }
}

// ---------------------------------------------------------------------------
// Launcher. Workspace: float4 cand[BATCH*NPTS] = 512 KB.
// ---------------------------------------------------------------------------
extern "C" void kernel_launch(void* const* d_in, const int* in_sizes, int n_in,
                              void* d_out, int out_size, void* d_ws, size_t ws_size,
                              hipStream_t stream)
{
    const float* xyz1  = (const float*)d_in[0];
    const float* xyz2  = (const float*)d_in[1];
    const float* flow1 = (const float*)d_in[2];
    float* out = (float*)d_out;

    float4* cand = (float4*)d_ws;

    prep_kernel<<<BATCH * NPTS / 256, 256, 0, stream>>>(xyz1, flow1, cand);
    scan_merge_kernel<<<BATCH * (NPTS / QPB), 256, 0, stream>>>(xyz2, flow1, cand, out);
}

// Round 5
// 120.923 us; speedup vs baseline: 3.4720x; 1.1246x over previous
//
#include <hip/hip_runtime.h>
#include <math.h>

#define BATCH 4
#define NPTS 8192
#define CH 512                 // candidates per LDS chunk (8 KB)

// ---------------------------------------------------------------------------
// Kernel 1: warp xyz1 by flow1, pack as (-2x, -2y, -2z, |c|^2): scan key is
// d' = |c|^2 - 2<c,q> (3 FMAs, same per-query ordering as |c-q|^2; identical
// expansion form to the reference's selection). Coords recovered exactly in
// the epilogue as x = -0.5 * c.x (power-of-two scale).
// ---------------------------------------------------------------------------
__global__ __launch_bounds__(256) void prep_kernel(
    const float* __restrict__ xyz1, const float* __restrict__ flow1,
    float4* __restrict__ cand)
{
    int t = blockIdx.x * 256 + threadIdx.x;        // BATCH*NPTS threads
    int b = t >> 13;
    int n = t & (NPTS - 1);
    const float* x = xyz1 + b * 3 * NPTS + n;
    const float* f = flow1 + b * 3 * NPTS + n;
    float wx = x[0]        + f[0];
    float wy = x[NPTS]     + f[NPTS];
    float wz = x[2 * NPTS] + f[2 * NPTS];
    float nrm = fmaf(wx, wx, fmaf(wy, wy, wz * wz));
    cand[t] = make_float4(-2.0f * wx, -2.0f * wy, -2.0f * wz, nrm);
}

// ---------------------------------------------------------------------------
// Kernel 2: LDS-broadcast partial 3-NN scan.
// Block = 256 threads = 256 queries (one per thread); block owns ONE candidate
// segment of NPTS/SEGS points, staged chunk-wise (512 cands = 8 KB) into LDS.
// All lanes read the SAME LDS address each step -> broadcast, conflict-free,
// on-CU (no L1 thrash, no L2 latency in the hot loop).
// Grid = BATCH * 32 * SEGS; SEGS=16 -> 2048 blocks = 8 blocks/CU (8 waves/EU).
// Strict '<' + ascending k preserves lowest-index-wins tie-break.
// ---------------------------------------------------------------------------
__global__ __launch_bounds__(256, 8) void scan_kernel(
    const float* __restrict__ xyz2, const float4* __restrict__ cand,
    float* __restrict__ pd, int* __restrict__ pi, int lgsegs)
{
    __shared__ float4 sc[CH];

    int SEGS   = 1 << lgsegs;
    int SEGLEN = NPTS >> lgsegs;
    int t   = (int)threadIdx.x;
    int seg = blockIdx.x & (SEGS - 1);
    int qt  = (blockIdx.x >> lgsegs) & 31;         // NPTS/256 = 32 query tiles
    int b   = blockIdx.x >> (lgsegs + 5);
    int j   = qt * 256 + t;

    const float* qp = xyz2 + b * 3 * NPTS + j;
    float qx = qp[0], qy = qp[NPTS], qz = qp[2 * NPTS];

    const float4* src = cand + b * NPTS + seg * SEGLEN;

    float e0 = 3.4e38f, e1 = 3.4e38f, e2 = 3.4e38f;
    int   i0 = 0, i1 = 0, i2 = 0;

    for (int cb = 0; cb < SEGLEN; cb += CH) {
        // stage 512 candidates (2 coalesced float4 loads/thread), issued early
        float4 r0 = src[cb + t];
        float4 r1 = src[cb + t + 256];
        __syncthreads();                 // previous chunk fully consumed
        sc[t]       = r0;
        sc[t + 256] = r1;
        __syncthreads();

        #pragma unroll 8
        for (int k = 0; k < CH; ++k) {
            float4 c = sc[k];            // same addr across all lanes: broadcast
            float d = fmaf(c.x, qx, fmaf(c.y, qy, fmaf(c.z, qz, c.w)));
            int kk = cb + k;
            bool c0 = d < e0, c1 = d < e1, c2 = d < e2;
            float ne1 = __builtin_amdgcn_fmed3f(e0, e1, d);  // 2nd smallest
            float ne2 = __builtin_amdgcn_fmed3f(e1, e2, d);  // 3rd smallest
            i2 = c1 ? i1 : (c2 ? kk : i2);
            i1 = c0 ? i0 : (c1 ? kk : i1);
            i0 = c0 ? kk : i0;
            e0 = fminf(e0, d);
            e1 = ne1; e2 = ne2;
        }
    }

    int off = seg * SEGLEN;
    size_t base = ((size_t)(b * SEGS + seg) * 3) * NPTS + j;   // [b][seg][slot][N]
    pd[base]            = e0;  pi[base]            = i0 + off;
    pd[base + NPTS]     = e1;  pi[base + NPTS]     = i1 + off;
    pd[base + 2 * NPTS] = e2;  pi[base + 2 * NPTS] = i2 + off;
}

// ---------------------------------------------------------------------------
// Kernel 3: merge SEGS partial top-3s per query (ascending segment order ->
// lowest global index wins ties), then inverse-distance-weight epilogue.
// ---------------------------------------------------------------------------
__device__ __forceinline__ void insert3(float d, int idx,
    float& e0, float& e1, float& e2, int& i0, int& i1, int& i2)
{
    if (d < e2) {
        bool c1 = d < e1, c0 = d < e0;
        e2 = c1 ? e1 : d;   i2 = c1 ? i1 : idx;
        e1 = c0 ? e0 : (c1 ? d : e1);
        i1 = c0 ? i0 : (c1 ? idx : i1);
        e0 = c0 ? d : e0;   i0 = c0 ? idx : i0;
    }
}

__global__ __launch_bounds__(256) void merge_kernel(
    const float* __restrict__ xyz2, const float* __restrict__ flow1,
    const float4* __restrict__ cand,
    const float* __restrict__ pd, const int* __restrict__ pi,
    float* __restrict__ out, int lgsegs)
{
    int g = blockIdx.x * 256 + (int)threadIdx.x;   // BATCH*NPTS threads
    int b = g >> 13;
    int j = g & (NPTS - 1);
    int SEGS = 1 << lgsegs;

    float m0 = 3.4e38f, m1 = 3.4e38f, m2 = 3.4e38f;
    int   n0 = 0, n1 = 0, n2 = 0;
    for (int s = 0; s < SEGS; ++s) {
        size_t base = ((size_t)(b * SEGS + s) * 3) * NPTS + j;
        insert3(pd[base],            pi[base],            m0, m1, m2, n0, n1, n2);
        insert3(pd[base + NPTS],     pi[base + NPTS],     m0, m1, m2, n0, n1, n2);
        insert3(pd[base + 2 * NPTS], pi[base + 2 * NPTS], m0, m1, m2, n0, n1, n2);
    }

    const float* qp = xyz2 + b * 3 * NPTS + j;
    float px = qp[0], py = qp[NPTS], pz = qp[2 * NPTS];

    const float4* cbb = cand + b * NPTS;
    const float*  fb  = flow1 + b * 3 * NPTS;

    float wsum = 0.f, f2x = 0.f, f2y = 0.f, f2z = 0.f;
    int idxs[3] = { n0, n1, n2 };
    #pragma unroll
    for (int k = 0; k < 3; ++k) {
        int id = idxs[k];
        float4 c = cbb[id];
        float cx = -0.5f * c.x, cy = -0.5f * c.y, cz = -0.5f * c.z;  // exact
        float dx = cx - px, dy = cy - py, dz = cz - pz;
        float dist = sqrtf(fmaf(dx, dx, fmaf(dy, dy, dz * dz)));
        dist = fmaxf(dist, 1e-10f);
        float w = 1.0f / dist;
        wsum += w;
        f2x = fmaf(w, fb[id],            f2x);
        f2y = fmaf(w, fb[NPTS + id],     f2y);
        f2z = fmaf(w, fb[2 * NPTS + id], f2z);
    }
    float r = 1.0f / wsum;
    float* ob = out + b * 3 * NPTS;
    ob[j]            = px - f2x * r;
    ob[NPTS + j]     = py - f2y * r;
    ob[2 * NPTS + j] = pz - f2z * r;
}

// ---------------------------------------------------------------------------
// Launcher. Workspace (adaptive SEGS by ws_size):
//   cand: 512 KB; pd: 384KB*SEGS; pi: 384KB*SEGS.
//   SEGS=16 needs 12.8 MB ... SEGS=2 needs 2.0 MiB (proven available in R0).
// ---------------------------------------------------------------------------
extern "C" void kernel_launch(void* const* d_in, const int* in_sizes, int n_in,
                              void* d_out, int out_size, void* d_ws, size_t ws_size,
                              hipStream_t stream)
{
    const float* xyz1  = (const float*)d_in[0];
    const float* xyz2  = (const float*)d_in[1];
    const float* flow1 = (const float*)d_in[2];
    float* out = (float*)d_out;

    const size_t CAND_BYTES = (size_t)BATCH * NPTS * sizeof(float4);   // 512 KB
    int lgsegs = 1;
    for (int lg = 4; lg >= 1; --lg) {
        size_t need = CAND_BYTES + (size_t)BATCH * NPTS * (1 << lg) * 3 * 8;
        if (need <= ws_size) { lgsegs = lg; break; }
    }
    int SEGS = 1 << lgsegs;
    size_t pd_bytes = (size_t)BATCH * NPTS * SEGS * 3 * sizeof(float);

    float4* cand = (float4*)d_ws;
    float*  pd   = (float*)((char*)d_ws + CAND_BYTES);
    int*    pi   = (int*)((char*)d_ws + CAND_BYTES + pd_bytes);

    prep_kernel <<<BATCH * NPTS / 256, 256, 0, stream>>>(xyz1, flow1, cand);
    scan_kernel <<<BATCH * 32 * SEGS,  256, 0, stream>>>(xyz2, cand, pd, pi, lgsegs);
    merge_kernel<<<BATCH * NPTS / 256, 256, 0, stream>>>(xyz2, flow1, cand, pd, pi, out, lgsegs);
}